// Round 11
// baseline (941.653 us; speedup 1.0000x reference)
//
#include <hip/hip_runtime.h>
#include <hip/hip_cooperative_groups.h>
#include <math.h>

namespace cg = cooperative_groups;

#define D 128
#define NT 256

__device__ __forceinline__ float wsum(float v) {
    v += __shfl_xor(v, 1, 64);
    v += __shfl_xor(v, 2, 64);
    v += __shfl_xor(v, 4, 64);
    v += __shfl_xor(v, 8, 64);
    v += __shfl_xor(v, 16, 64);
    v += __shfl_xor(v, 32, 64);
    return v;
}

__device__ __forceinline__ float hsum32(float v) {
    v += __shfl_xor(v, 1, 64);
    v += __shfl_xor(v, 2, 64);
    v += __shfl_xor(v, 4, 64);
    v += __shfl_xor(v, 8, 64);
    v += __shfl_xor(v, 16, 64);
    return v;
}

__device__ __forceinline__ float4 ld4(const float* p) { return *(const float4*)p; }
__device__ __forceinline__ float dot4(float4 a, float4 b) {
    return fmaf(a.x, b.x, fmaf(a.y, b.y, fmaf(a.z, b.z, a.w * b.w)));
}

__device__ __forceinline__ unsigned int bf16rne(float f) {
    unsigned int u = __float_as_uint(f);
    return (u + 0x7fffu + ((u >> 16) & 1u)) >> 16;
}

struct Params {
    const float* x; const int* adj; const float* ea; const float* W;
    const float* bias; const float* attw;
    float* xt; float* a1; float* a2; float* hb; float* hbsc; float* Wt;
    unsigned int* eb; int2* row_pairs; int* col_edges;
    int* flag; int* cnt_r; int* cnt_c; int* cur_r; int* cur_c;
    int* start_r; int* start_c; int* partial;
    int N, E, P1B, G;
};

// ================================================================ megak: persistent cooperative front-end
__global__ __launch_bounds__(256, 8) void megak(Params p) {
    cg::grid_group grid = cg::this_grid();
    const int b = blockIdx.x;
    const int t = threadIdx.x;
    const int G = p.G;
    __shared__ float Xs[32][128];
    int* smi = (int*)&Xs[0][0];

    // ---------------- P0: zero counters | detect | bias | transpose-W
    for (int i = b * NT + t; i < 2 * p.N; i += G * NT) p.cnt_r[i] = 0;  // cnt_r|cnt_c contiguous
    if (b == 0 && t < 64) {
        int v = p.adj[2 * t + 1];
        unsigned long long m = __ballot(v != 0);
        if (t == 0) *p.flag = (m == 0ULL) ? 1 : 0;
    }
    if (b == 1 && t < 64) {
        float b0 = p.bias[t], b1 = p.bias[t + 64];
        float n2f = wsum(b0 * b0 + b1 * b1);
        float n  = fmaxf(sqrtf(n2f), 1e-15f);
        float th = tanhf(n);
        float sc = th / n;
        float nn = th;
        if (nn > 0.996f) { sc *= 0.996f / nn; nn = 0.996f; }
        float h0 = sc * b0, h1 = sc * b1;
        p.hb[t] = h0; p.hb[t + 64] = h1;
        float s1 = wsum(p.attw[t] * h0 + p.attw[t + 64] * h1);
        float s2 = wsum(p.attw[128 + t] * h0 + p.attw[192 + t] * h1);
        if (t == 0) { p.hbsc[0] = nn * nn; p.hbsc[1] = s1; p.hbsc[2] = s2; }
    }
    if (b >= 2 && b < 6) {
        int tb = b - 2;
        int c = t & 127;
        int k0 = tb * 32 + (t >> 7) * 16;
        float v[16];
#pragma unroll
        for (int j = 0; j < 4; ++j) {
            float4 r = ld4(p.W + (size_t)c * D + k0 + 4 * j);
            v[4 * j] = r.x; v[4 * j + 1] = r.y; v[4 * j + 2] = r.z; v[4 * j + 3] = r.w;
        }
#pragma unroll
        for (int j = 0; j < 16; ++j)
            p.Wt[(size_t)(k0 + j) * D + c] = v[j];
    }
    grid.sync();

    // ---------------- PA: convert (3/8) | phase1 (3/8) | count (2/8)
    {
        const int r8 = b & 7;
        const int grp = b >> 3;
        const int NG = G >> 3;
        if (r8 < 3) {
            // convert: float4 -> bf16x2 uint2
            const long long F4 = (long long)p.E * (D / 4);
            const long long CB = 3LL * NG;
            const long long stride = CB * NT;
            const float4* ea4 = (const float4*)p.ea;
            uint2* eb2 = (uint2*)p.eb;
            long long f = (long long)(grp * 3 + r8) * NT + t;
            for (; f + stride < F4; f += 2 * stride) {
                float4 v0 = ea4[f];
                float4 v1 = ea4[f + stride];
                uint2 o0, o1;
                o0.x = bf16rne(v0.x) | (bf16rne(v0.y) << 16); o0.y = bf16rne(v0.z) | (bf16rne(v0.w) << 16);
                o1.x = bf16rne(v1.x) | (bf16rne(v1.y) << 16); o1.y = bf16rne(v1.z) | (bf16rne(v1.w) << 16);
                eb2[f] = o0; eb2[f + stride] = o1;
            }
            for (; f < F4; f += stride) {
                float4 v = ea4[f];
                uint2 o;
                o.x = bf16rne(v.x) | (bf16rne(v.y) << 16);
                o.y = bf16rne(v.z) | (bf16rne(v.w) << 16);
                eb2[f] = o;
            }
        } else if (r8 < 6) {
            // phase1: grid-stride over 32-node tiles
            const int PH = 3 * NG;
            for (int tile = grp * 3 + (r8 - 3); tile < p.P1B; tile += PH) {
                const int node0 = tile * 32;
                {
                    int r = t >> 3;
                    int cb4 = (t & 7) * 16;
                    int gi = node0 + r;
                    if (gi < p.N) {
                        const float* src = p.x + (size_t)gi * D + cb4;
#pragma unroll
                        for (int j = 0; j < 4; ++j)
                            *(float4*)&Xs[r][cb4 + 4 * j] = ld4(src + 4 * j);
                    } else {
                        float4 z = make_float4(0.f, 0.f, 0.f, 0.f);
#pragma unroll
                        for (int j = 0; j < 4; ++j)
                            *(float4*)&Xs[r][cb4 + 4 * j] = z;
                    }
                }
                __syncthreads();

                const int g  = t >> 5;
                const int cq = (t & 31) << 2;

                float acc[4][4];
#pragma unroll
                for (int n = 0; n < 4; ++n)
#pragma unroll
                    for (int c = 0; c < 4; ++c) acc[n][c] = 0.f;

                for (int k = 0; k < D; k += 4) {
                    float4 w0 = ld4(p.Wt + (size_t)(k + 0) * D + cq);
                    float4 w1 = ld4(p.Wt + (size_t)(k + 1) * D + cq);
                    float4 w2 = ld4(p.Wt + (size_t)(k + 2) * D + cq);
                    float4 w3 = ld4(p.Wt + (size_t)(k + 3) * D + cq);
#pragma unroll
                    for (int n = 0; n < 4; ++n) {
                        float4 xk = *(const float4*)&Xs[g * 4 + n][k];
                        acc[n][0] = fmaf(xk.x, w0.x, fmaf(xk.y, w1.x, fmaf(xk.z, w2.x, fmaf(xk.w, w3.x, acc[n][0]))));
                        acc[n][1] = fmaf(xk.x, w0.y, fmaf(xk.y, w1.y, fmaf(xk.z, w2.y, fmaf(xk.w, w3.y, acc[n][1]))));
                        acc[n][2] = fmaf(xk.x, w0.z, fmaf(xk.y, w1.z, fmaf(xk.z, w2.z, fmaf(xk.w, w3.z, acc[n][2]))));
                        acc[n][3] = fmaf(xk.x, w0.w, fmaf(xk.y, w1.w, fmaf(xk.z, w2.w, fmaf(xk.w, w3.w, acc[n][3]))));
                    }
                }

                float4 hb4 = ld4(p.hb + cq);
                float4 w14 = ld4(p.attw + cq);
                float4 w24 = ld4(p.attw + 128 + cq);
                const float hb2 = p.hbsc[0], s1 = p.hbsc[1], s2 = p.hbsc[2];

#pragma unroll
                for (int n = 0; n < 4; ++n) {
                    const int i = node0 + g * 4 + n;
                    float4 mx = make_float4(acc[n][0], acc[n][1], acc[n][2], acc[n][3]);
                    float4 xv = *(const float4*)&Xs[g * 4 + n][cq];

                    float xn2  = hsum32(dot4(xv, xv));
                    float mxn2 = hsum32(dot4(mx, mx));
                    float dmb  = hsum32(dot4(mx, hb4));
                    float r1   = hsum32(dot4(mx, w14));
                    float r2   = hsum32(dot4(mx, w24));

                    float xn  = fmaxf(sqrtf(xn2), 1e-15f);
                    float mxn = fmaxf(sqrtf(mxn2), 1e-15f);
                    float art = atanhf(fminf(xn, 1.f - 1e-7f));
                    float th  = tanhf(mxn / xn * art);
                    float hnorm = fminf(th, 0.996f);
                    float alpha = hnorm / mxn;
                    float x2 = hnorm * hnorm, xy = alpha * dmb;
                    float den = fmaxf(1.f + 2.f * xy + x2 * hb2, 1e-15f);
                    float cA = (1.f + 2.f * xy + hb2) / den * alpha;
                    float cB = (1.f - x2) / den;
                    float h2n2 = cA * cA * mxn2 + 2.f * cA * cB * dmb + cB * cB * hb2;
                    float h2n = fmaxf(sqrtf(h2n2), 1e-15f);
                    if (h2n > 0.996f) { float sl = 0.996f / h2n; cA *= sl; cB *= sl; h2n = 0.996f; }
                    float gg = atanhf(fminf(h2n, 1.f - 1e-7f)) / h2n;
                    cA *= gg; cB *= gg;

                    if (i < p.N) {
                        float4 o;
                        o.x = cA * mx.x + cB * hb4.x; o.y = cA * mx.y + cB * hb4.y;
                        o.z = cA * mx.z + cB * hb4.z; o.w = cA * mx.w + cB * hb4.w;
                        *(float4*)(p.xt + (size_t)i * D + cq) = o;
                        if ((t & 31) == 0) {
                            p.a1[i] = cA * r1 + cB * s1;
                            p.a2[i] = cA * r2 + cB * s2;
                        }
                    }
                }
                __syncthreads();
            }
        } else {
            // count
            const int is64 = *p.flag;
            const int CT = 2 * NG;
            for (int e = (grp * 2 + (r8 - 6)) * NT + t; e < p.E; e += CT * NT) {
                int r, c;
                if (is64) { r = p.adj[(size_t)2 * e]; c = p.adj[2 * ((size_t)p.E + e)]; }
                else      { r = p.adj[e];             c = p.adj[(size_t)p.E + e]; }
                atomicAdd(&p.cnt_r[r], 1);
                atomicAdd(&p.cnt_c[c], 1);
            }
        }
    }
    grid.sync();

    // ---------------- PB: two-level exclusive scan of cnt_r and cnt_c
    const int NCH = (p.N + NT - 1) / NT;   // chunks per array
    int myv = 0, myincl = 0;
    if (b < 2 * NCH) {
        const int* cnt = (b < NCH) ? p.cnt_r : p.cnt_c;
        const int chunk = (b < NCH) ? b : (b - NCH);
        const int i = chunk * NT + t;
        myv = (i < p.N) ? cnt[i] : 0;
        smi[t] = myv;
        __syncthreads();
        for (int off = 1; off < NT; off <<= 1) {
            int u = (t >= off) ? smi[t - off] : 0;
            __syncthreads();
            smi[t] += u;
            __syncthreads();
        }
        myincl = smi[t];
        if (t == NT - 1) p.partial[b] = myincl;   // chunk total
    }
    grid.sync();
    if (b < 2) {
        const int off0 = (b == 0) ? 0 : NCH;
        int v2 = (t < NCH) ? p.partial[off0 + t] : 0;
        smi[t] = v2;
        __syncthreads();
        for (int off = 1; off < NT; off <<= 1) {
            int u = (t >= off) ? smi[t - off] : 0;
            __syncthreads();
            smi[t] += u;
            __syncthreads();
        }
        if (t < NCH) p.partial[off0 + t] = smi[t] - v2;   // exclusive base per chunk
    }
    grid.sync();
    if (b < 2 * NCH) {
        const int base = p.partial[b];
        const int chunk = (b < NCH) ? b : (b - NCH);
        const int i = chunk * NT + t;
        if (i < p.N) {
            int ex = base + myincl - myv;
            if (b < NCH) { p.start_r[i] = ex; p.cur_r[i] = ex; }
            else         { p.start_c[i] = ex; p.cur_c[i] = ex; }
        }
    }
    if (b == 0 && t == 0) { p.start_r[p.N] = p.E; p.start_c[p.N] = p.E; }
    grid.sync();

    // ---------------- PC: CSR fill (a2 packed into row_pairs)
    {
        const int is64 = *p.flag;
        for (int e = b * NT + t; e < p.E; e += G * NT) {
            int r, c;
            if (is64) { r = p.adj[(size_t)2 * e]; c = p.adj[2 * ((size_t)p.E + e)]; }
            else      { r = p.adj[e];             c = p.adj[(size_t)p.E + e]; }
            int pp = atomicAdd(&p.cur_r[r], 1);
            p.row_pairs[pp] = make_int2(e, __float_as_int(p.a2[c]));
            int q = atomicAdd(&p.cur_c[c], 1);
            p.col_edges[q] = e;
        }
    }
}

// ================================================================ gatherk: R5-style (full wave per edge, 8 in flight)
__global__ __launch_bounds__(256) void gatherk(const unsigned int* __restrict__ eb,
                                               const float* __restrict__ attw,
                                               const float* __restrict__ attb,
                                               const float* __restrict__ xt,
                                               const float* __restrict__ a1,
                                               const int* __restrict__ start_r,
                                               const int* __restrict__ start_c,
                                               const int2* __restrict__ row_pairs,
                                               const int* __restrict__ col_edges,
                                               float* __restrict__ out,
                                               int N) {
    const int lane = threadIdx.x & 63;
    const int node = (blockIdx.x * blockDim.x + threadIdx.x) >> 6;
    if (node >= N) return;

    const int rs = start_r[node], re = start_r[node + 1];
    const int cs = start_c[node], ce = start_c[node + 1];

    float r0 = 0.f, r1 = 0.f;
    float sa2 = 0.f;
    int j = rs;
    for (; j + 8 <= re; j += 8) {
        int2 pr[8];
#pragma unroll
        for (int k = 0; k < 8; ++k) pr[k] = row_pairs[j + k];
        unsigned int q[8];
#pragma unroll
        for (int k = 0; k < 8; ++k) q[k] = eb[(size_t)pr[k].x * 64 + lane];
#pragma unroll
        for (int k = 0; k < 8; ++k) {
            sa2 += __int_as_float(pr[k].y);
            r0 += __uint_as_float(q[k] << 16);
            r1 += __uint_as_float(q[k] & 0xffff0000u);
        }
    }
    for (; j < re; ++j) {
        int2 p0 = row_pairs[j];
        unsigned int q0 = eb[(size_t)p0.x * 64 + lane];
        sa2 += __int_as_float(p0.y);
        r0 += __uint_as_float(q0 << 16);
        r1 += __uint_as_float(q0 & 0xffff0000u);
    }

    float c0 = 0.f, c1 = 0.f;
    j = cs;
    for (; j + 8 <= ce; j += 8) {
        int ei[8];
#pragma unroll
        for (int k = 0; k < 8; ++k) ei[k] = col_edges[j + k];
        unsigned int q[8];
#pragma unroll
        for (int k = 0; k < 8; ++k) q[k] = eb[(size_t)ei[k] * 64 + lane];
#pragma unroll
        for (int k = 0; k < 8; ++k) {
            c0 += __uint_as_float(q[k] << 16);
            c1 += __uint_as_float(q[k] & 0xffff0000u);
        }
    }
    for (; j < ce; ++j) {
        int e0 = col_edges[j];
        unsigned int q0 = eb[(size_t)e0 * 64 + lane];
        c0 += __uint_as_float(q0 << 16);
        c1 += __uint_as_float(q0 & 0xffff0000u);
    }

    float2 w3 = *(const float2*)(attw + 256 + 2 * lane);
    float d3 = wsum(r0 * w3.x + r1 * w3.y);

    float degr = (float)(re - rs), degc = (float)(ce - cs);
    float satt = degr * (a1[node] + attb[0]) + sa2 + d3;
    float mr = 1.f / fmaxf(degr, 1.f);
    float mc = 1.f / fmaxf(degc, 1.f);

    float2 xv = *(const float2*)(xt + (size_t)node * D + 2 * lane);
    float s0 = fmaf(xv.x, satt, xv.x) + r0 * mr + c0 * mc;
    float s1 = fmaf(xv.y, satt, xv.y) + r1 * mr + c1 * mc;

    float n1 = fmaxf(sqrtf(wsum(s0 * s0 + s1 * s1)), 1e-15f);
    float th1 = tanhf(n1);
    float nrm1 = fminf(th1, 0.996f);
    float sc1 = nrm1 / n1;
    float lam = atanhf(fminf(nrm1, 1.f - 1e-7f)) / nrm1 * sc1;
    float t0 = fmaxf(lam * s0, 0.f);
    float t1 = fmaxf(lam * s1, 0.f);
    float n2 = fmaxf(sqrtf(wsum(t0 * t0 + t1 * t1)), 1e-15f);
    float th2 = tanhf(n2);
    float sc2 = fminf(th2, 0.996f) / n2;

    float2 o; o.x = sc2 * t0; o.y = sc2 * t1;
    *(float2*)(out + (size_t)node * D + 2 * lane) = o;
}

// ----------------------------------------------------------------
extern "C" void kernel_launch(void* const* d_in, const int* in_sizes, int n_in,
                              void* d_out, int out_size, void* d_ws, size_t ws_size,
                              hipStream_t stream) {
    const float* x    = (const float*)d_in[0];
    const int*   adj  = (const int*)d_in[1];
    const float* ea   = (const float*)d_in[2];
    const float* W    = (const float*)d_in[3];
    const float* bias = (const float*)d_in[4];
    const float* attw = (const float*)d_in[5];
    const float* attb = (const float*)d_in[6];
    float* out = (float*)d_out;

    const int N = in_sizes[0] / D;   // 50000
    const int E = in_sizes[2] / D;   // 800000

    float* ws = (float*)d_ws;
    float* xt   = ws;  ws += (size_t)N * D;
    float* a1   = ws;  ws += N;
    float* a2   = ws;  ws += N;
    float* hb   = ws;  ws += D;
    float* hbsc = ws;  ws += 4;
    float* Wt   = ws;  ws += D * D;
    unsigned int* eb = (unsigned int*)ws;  ws += (size_t)E * (D / 2);
    int2* row_pairs  = (int2*)ws;          ws += (size_t)E * 2;
    int* iws = (int*)ws;
    int* col_edges = iws; iws += E;
    int* flag    = iws;  iws += 4;
    int* cnt_r   = iws;  iws += N;   // cnt_r|cnt_c contiguous
    int* cnt_c   = iws;  iws += N;
    int* cur_r   = iws;  iws += N;
    int* cur_c   = iws;  iws += N;
    int* start_r = iws;  iws += N + 1;
    int* start_c = iws;  iws += N + 1;
    int* partial = iws;  iws += 512;

    // grid size: all blocks co-resident (cooperative requirement)
    int occ = 0;
    hipOccupancyMaxActiveBlocksPerMultiprocessor(&occ, (const void*)megak, NT, 0);
    int nCU = 0;
    hipDeviceGetAttribute(&nCU, hipDeviceAttributeMultiprocessorCount, 0);
    if (occ < 1) occ = 1;
    if (nCU < 1) nCU = 256;
    int G = occ * nCU;
    if (G > 2048) G = 2048;
    G &= ~7;
    if (G < 512) G = 512;

    Params prm;
    prm.x = x; prm.adj = adj; prm.ea = ea; prm.W = W; prm.bias = bias; prm.attw = attw;
    prm.xt = xt; prm.a1 = a1; prm.a2 = a2; prm.hb = hb; prm.hbsc = hbsc; prm.Wt = Wt;
    prm.eb = eb; prm.row_pairs = row_pairs; prm.col_edges = col_edges;
    prm.flag = flag; prm.cnt_r = cnt_r; prm.cnt_c = cnt_c; prm.cur_r = cur_r; prm.cur_c = cur_c;
    prm.start_r = start_r; prm.start_c = start_c; prm.partial = partial;
    prm.N = N; prm.E = E; prm.P1B = (N + 31) / 32; prm.G = G;

    void* args[] = { &prm };
    hipLaunchCooperativeKernel((const void*)megak, dim3(G), dim3(NT), args, 0, stream);

    gatherk<<<(N * 64 + 255) / 256, 256, 0, stream>>>(eb, attw, attb, xt, a1,
                                                      start_r, start_c, row_pairs, col_edges,
                                                      out, N);
}

// Round 12
// 462.679 us; speedup vs baseline: 2.0352x; 2.0352x over previous
//
#include <hip/hip_runtime.h>
#include <math.h>

#define D 128

__device__ __forceinline__ float wsum(float v) {
    v += __shfl_xor(v, 1, 64);
    v += __shfl_xor(v, 2, 64);
    v += __shfl_xor(v, 4, 64);
    v += __shfl_xor(v, 8, 64);
    v += __shfl_xor(v, 16, 64);
    v += __shfl_xor(v, 32, 64);
    return v;
}

__device__ __forceinline__ float hsum32(float v) {
    v += __shfl_xor(v, 1, 64);
    v += __shfl_xor(v, 2, 64);
    v += __shfl_xor(v, 4, 64);
    v += __shfl_xor(v, 8, 64);
    v += __shfl_xor(v, 16, 64);
    return v;
}

__device__ __forceinline__ float4 ld4(const float* p) { return *(const float4*)p; }
__device__ __forceinline__ float dot4(float4 a, float4 b) {
    return fmaf(a.x, b.x, fmaf(a.y, b.y, fmaf(a.z, b.z, a.w * b.w)));
}

__device__ __forceinline__ unsigned int bf16rne(float f) {
    unsigned int u = __float_as_uint(f);
    return (u + 0x7fffu + ((u >> 16) & 1u)) >> 16;
}

// ---------------------------------------------------------------- K1: zero | detect | bias | transpose-W
__global__ __launch_bounds__(256) void initk(const int* __restrict__ adj,
                                             const float* __restrict__ bias,
                                             const float* __restrict__ attw,
                                             const float* __restrict__ W,
                                             int* __restrict__ cnt,   // 2N ints
                                             int* __restrict__ flag,
                                             float* __restrict__ hb,
                                             float* __restrict__ hbsc,
                                             float* __restrict__ Wt,
                                             int n2, int ZB) {
    const int b = blockIdx.x;
    const int t = threadIdx.x;
    if (b < ZB) {
        int i = b * 256 + t;
        if (i < n2) cnt[i] = 0;
    } else if (b == ZB) {
        if (t < 64) {
            int v = adj[2 * t + 1];
            unsigned long long m = __ballot(v != 0);
            if (t == 0) *flag = (m == 0ULL) ? 1 : 0;
        }
    } else if (b == ZB + 1) {
        if (t < 64) {
            float b0 = bias[t], b1 = bias[t + 64];
            float n2f = wsum(b0 * b0 + b1 * b1);
            float n  = fmaxf(sqrtf(n2f), 1e-15f);
            float th = tanhf(n);
            float sc = th / n;
            float nn = th;
            if (nn > 0.996f) { sc *= 0.996f / nn; nn = 0.996f; }
            float h0 = sc * b0, h1 = sc * b1;
            hb[t] = h0; hb[t + 64] = h1;
            float s1 = wsum(attw[t] * h0 + attw[t + 64] * h1);
            float s2 = wsum(attw[128 + t] * h0 + attw[192 + t] * h1);
            if (t == 0) { hbsc[0] = nn * nn; hbsc[1] = s1; hbsc[2] = s2; }
        }
    } else {
        // transpose: 4 blocks, each 32 k-rows of Wt (Wt[k][c] = W[c][k])
        int tb = b - (ZB + 2);              // 0..3
        int c = t & 127;
        int k0 = tb * 32 + (t >> 7) * 16;
        float v[16];
#pragma unroll
        for (int j = 0; j < 4; ++j) {
            float4 r = ld4(W + (size_t)c * D + k0 + 4 * j);
            v[4 * j] = r.x; v[4 * j + 1] = r.y; v[4 * j + 2] = r.z; v[4 * j + 3] = r.w;
        }
#pragma unroll
        for (int j = 0; j < 16; ++j)
            Wt[(size_t)(k0 + j) * D + c] = v[j];
    }
}

// ---------------------------------------------------------------- convert helper: [f0, f1) strided
__device__ __forceinline__ void convert_range(const float* __restrict__ ea,
                                              unsigned int* __restrict__ eb,
                                              long long f, long long f1, long long stride) {
    const float4* ea4 = (const float4*)ea;
    uint2* eb2 = (uint2*)eb;
    for (; f + stride < f1; f += 2 * stride) {
        float4 v0 = ea4[f];
        float4 v1 = ea4[f + stride];
        uint2 o0, o1;
        o0.x = bf16rne(v0.x) | (bf16rne(v0.y) << 16); o0.y = bf16rne(v0.z) | (bf16rne(v0.w) << 16);
        o1.x = bf16rne(v1.x) | (bf16rne(v1.y) << 16); o1.y = bf16rne(v1.z) | (bf16rne(v1.w) << 16);
        eb2[f] = o0; eb2[f + stride] = o1;
    }
    if (f < f1) {
        float4 v = ea4[f];
        uint2 o;
        o.x = bf16rne(v.x) | (bf16rne(v.y) << 16);
        o.y = bf16rne(v.z) | (bf16rne(v.w) << 16);
        eb2[f] = o;
    }
}

// ---------------------------------------------------------------- K2: fusedA2 = phase1 (3/8) | count (1/8) | convert-half1 (4/8)
__global__ __launch_bounds__(256) void fusedA2(const float* __restrict__ x,
                                               const float* __restrict__ Wt,
                                               const float* __restrict__ attw,
                                               const float* __restrict__ hb,
                                               const float* __restrict__ hbsc,
                                               const int* __restrict__ adj,
                                               const float* __restrict__ ea,
                                               const int* __restrict__ flag,
                                               float* __restrict__ xt,
                                               float* __restrict__ a1o,
                                               float* __restrict__ a2o,
                                               int* __restrict__ cnt_r,
                                               int* __restrict__ cnt_c,
                                               unsigned int* __restrict__ eb,
                                               int N, int E, int NG, int P1B) {
    const int b = blockIdx.x;
    const int t = threadIdx.x;
    const int r8 = b & 7;
    const int grp = b >> 3;
    __shared__ float Xs[32][128];

    if (r8 == 3) {
        // ------- count role (NG blocks)
        const int is64 = *flag;
        const int stride = NG * 256;
        for (int e = grp * 256 + t; e < E; e += stride) {
            int r, c;
            if (is64) { r = adj[(size_t)2 * e]; c = adj[2 * ((size_t)E + e)]; }
            else      { r = adj[e];             c = adj[(size_t)E + e]; }
            atomicAdd(&cnt_r[r], 1);
            atomicAdd(&cnt_c[c], 1);
        }
        return;
    }
    if (r8 >= 4) {
        // ------- convert role, first half of F4 (4*NG blocks)
        const long long F4 = (long long)E * (D / 4);
        const long long half = F4 / 2;
        const long long stride = 4LL * NG * 256;
        convert_range(ea, eb, (long long)(grp * 4 + (r8 - 4)) * 256 + t, half, stride);
        return;
    }

    // ------- phase1 role (3*NG blocks, grid-stride over tiles)
    const int PH = 3 * NG;
    for (int tile = grp * 3 + r8; tile < P1B; tile += PH) {
        const int node0 = tile * 32;
        {
            int r = t >> 3;
            int cb4 = (t & 7) * 16;
            int gi = node0 + r;
            if (gi < N) {
                const float* src = x + (size_t)gi * D + cb4;
#pragma unroll
                for (int j = 0; j < 4; ++j)
                    *(float4*)&Xs[r][cb4 + 4 * j] = ld4(src + 4 * j);
            } else {
                float4 z = make_float4(0.f, 0.f, 0.f, 0.f);
#pragma unroll
                for (int j = 0; j < 4; ++j)
                    *(float4*)&Xs[r][cb4 + 4 * j] = z;
            }
        }
        __syncthreads();

        const int g  = t >> 5;
        const int cq = (t & 31) << 2;

        float acc[4][4];
#pragma unroll
        for (int n = 0; n < 4; ++n)
#pragma unroll
            for (int c = 0; c < 4; ++c) acc[n][c] = 0.f;

        for (int k = 0; k < D; k += 4) {
            float4 w0 = ld4(Wt + (size_t)(k + 0) * D + cq);
            float4 w1 = ld4(Wt + (size_t)(k + 1) * D + cq);
            float4 w2 = ld4(Wt + (size_t)(k + 2) * D + cq);
            float4 w3 = ld4(Wt + (size_t)(k + 3) * D + cq);
#pragma unroll
            for (int n = 0; n < 4; ++n) {
                float4 xk = *(const float4*)&Xs[g * 4 + n][k];
                acc[n][0] = fmaf(xk.x, w0.x, fmaf(xk.y, w1.x, fmaf(xk.z, w2.x, fmaf(xk.w, w3.x, acc[n][0]))));
                acc[n][1] = fmaf(xk.x, w0.y, fmaf(xk.y, w1.y, fmaf(xk.z, w2.y, fmaf(xk.w, w3.y, acc[n][1]))));
                acc[n][2] = fmaf(xk.x, w0.z, fmaf(xk.y, w1.z, fmaf(xk.z, w2.z, fmaf(xk.w, w3.z, acc[n][2]))));
                acc[n][3] = fmaf(xk.x, w0.w, fmaf(xk.y, w1.w, fmaf(xk.z, w2.w, fmaf(xk.w, w3.w, acc[n][3]))));
            }
        }

        float4 hb4 = ld4(hb + cq);
        float4 w14 = ld4(attw + cq);
        float4 w24 = ld4(attw + 128 + cq);
        const float hb2 = hbsc[0], s1 = hbsc[1], s2 = hbsc[2];

#pragma unroll
        for (int n = 0; n < 4; ++n) {
            const int i = node0 + g * 4 + n;
            float4 mx = make_float4(acc[n][0], acc[n][1], acc[n][2], acc[n][3]);
            float4 xv = *(const float4*)&Xs[g * 4 + n][cq];

            float xn2  = hsum32(dot4(xv, xv));
            float mxn2 = hsum32(dot4(mx, mx));
            float dmb  = hsum32(dot4(mx, hb4));
            float r1   = hsum32(dot4(mx, w14));
            float r2   = hsum32(dot4(mx, w24));

            float xn  = fmaxf(sqrtf(xn2), 1e-15f);
            float mxn = fmaxf(sqrtf(mxn2), 1e-15f);
            float art = atanhf(fminf(xn, 1.f - 1e-7f));
            float th  = tanhf(mxn / xn * art);
            float hnorm = fminf(th, 0.996f);
            float alpha = hnorm / mxn;
            float x2 = hnorm * hnorm, xy = alpha * dmb;
            float den = fmaxf(1.f + 2.f * xy + x2 * hb2, 1e-15f);
            float cA = (1.f + 2.f * xy + hb2) / den * alpha;
            float cB = (1.f - x2) / den;
            float h2n2 = cA * cA * mxn2 + 2.f * cA * cB * dmb + cB * cB * hb2;
            float h2n = fmaxf(sqrtf(h2n2), 1e-15f);
            if (h2n > 0.996f) { float sl = 0.996f / h2n; cA *= sl; cB *= sl; h2n = 0.996f; }
            float gg = atanhf(fminf(h2n, 1.f - 1e-7f)) / h2n;
            cA *= gg; cB *= gg;

            if (i < N) {
                float4 o;
                o.x = cA * mx.x + cB * hb4.x; o.y = cA * mx.y + cB * hb4.y;
                o.z = cA * mx.z + cB * hb4.z; o.w = cA * mx.w + cB * hb4.w;
                *(float4*)(xt + (size_t)i * D + cq) = o;
                if ((t & 31) == 0) {
                    a1o[i] = cA * r1 + cB * s1;
                    a2o[i] = cA * r2 + cB * s2;
                }
            }
        }
        __syncthreads();
    }
}

// ---------------------------------------------------------------- K3: exclusive scan
__global__ __launch_bounds__(1024) void scank(const int* __restrict__ cnt_r,
                                              const int* __restrict__ cnt_c,
                                              int* __restrict__ start_r,
                                              int* __restrict__ start_c,
                                              int* __restrict__ cur_r,
                                              int* __restrict__ cur_c,
                                              int N) {
    const int* cnt  = blockIdx.x == 0 ? cnt_r : cnt_c;
    int* start      = blockIdx.x == 0 ? start_r : start_c;
    int* cur        = blockIdx.x == 0 ? cur_r : cur_c;
    const int t = threadIdx.x;
    const int NT = 1024;
    const int CH = (N + NT - 1) / NT;
    const int lo = t * CH;
    int hi = lo + CH; if (hi > N) hi = N;

    int local = 0;
    for (int i = lo; i < hi; ++i) local += cnt[i];

    __shared__ int sm[1024];
    sm[t] = local;
    __syncthreads();
    for (int off = 1; off < 1024; off <<= 1) {
        int v = (t >= off) ? sm[t - off] : 0;
        __syncthreads();
        sm[t] += v;
        __syncthreads();
    }
    int run = sm[t] - local;
    for (int i = lo; i < hi; ++i) {
        start[i] = run;
        cur[i] = run;
        run += cnt[i];
    }
    if (t == NT - 1) start[N] = sm[NT - 1];
}

// ---------------------------------------------------------------- K4: fusedD = fill (2/4) | convert-half2 (2/4)
__global__ __launch_bounds__(256) void fusedD(const int* __restrict__ adj,
                                              const float* __restrict__ a2,
                                              const float* __restrict__ ea,
                                              int* __restrict__ cur_r,
                                              int* __restrict__ cur_c,
                                              int2* __restrict__ row_pairs,
                                              int* __restrict__ col_edges,
                                              unsigned int* __restrict__ eb,
                                              const int* __restrict__ flag,
                                              int E, int NG) {
    const int b = blockIdx.x;
    const int t = threadIdx.x;
    const int r4 = b & 3;
    const int grp = b >> 2;

    if (r4 < 2) {
        // ------- fill role (2*NG blocks, grid-stride): store (edge, a2bits)
        const int is64 = *flag;
        const int stride = 2 * NG * 256;
        for (int e = (grp * 2 + r4) * 256 + t; e < E; e += stride) {
            int r, c;
            if (is64) { r = adj[(size_t)2 * e]; c = adj[2 * ((size_t)E + e)]; }
            else      { r = adj[e];             c = adj[(size_t)E + e]; }
            int p = atomicAdd(&cur_r[r], 1);
            row_pairs[p] = make_int2(e, __float_as_int(a2[c]));
            int q = atomicAdd(&cur_c[c], 1);
            col_edges[q] = e;
        }
    } else {
        // ------- convert role, second half of F4 (2*NG blocks)
        const long long F4 = (long long)E * (D / 4);
        const long long half = F4 / 2;
        const long long stride = 2LL * NG * 256;
        convert_range(ea, eb, half + (long long)(grp * 2 + (r4 - 2)) * 256 + t, F4, stride);
    }
}

// ---------------------------------------------------------------- K5: gather (R5-proven: full wave per edge, 8 in flight)
__global__ __launch_bounds__(256) void gatherk(const unsigned int* __restrict__ eb,
                                               const float* __restrict__ attw,
                                               const float* __restrict__ attb,
                                               const float* __restrict__ xt,
                                               const float* __restrict__ a1,
                                               const int* __restrict__ start_r,
                                               const int* __restrict__ start_c,
                                               const int2* __restrict__ row_pairs,
                                               const int* __restrict__ col_edges,
                                               float* __restrict__ out,
                                               int N) {
    const int lane = threadIdx.x & 63;
    const int node = (blockIdx.x * blockDim.x + threadIdx.x) >> 6;
    if (node >= N) return;

    const int rs = start_r[node], re = start_r[node + 1];
    const int cs = start_c[node], ce = start_c[node + 1];

    float r0 = 0.f, r1 = 0.f;
    float sa2 = 0.f;
    int j = rs;
    for (; j + 8 <= re; j += 8) {
        int2 pr[8];
#pragma unroll
        for (int k = 0; k < 8; ++k) pr[k] = row_pairs[j + k];
        unsigned int q[8];
#pragma unroll
        for (int k = 0; k < 8; ++k) q[k] = eb[(size_t)pr[k].x * 64 + lane];
#pragma unroll
        for (int k = 0; k < 8; ++k) {
            sa2 += __int_as_float(pr[k].y);
            r0 += __uint_as_float(q[k] << 16);
            r1 += __uint_as_float(q[k] & 0xffff0000u);
        }
    }
    for (; j < re; ++j) {
        int2 p0 = row_pairs[j];
        unsigned int q0 = eb[(size_t)p0.x * 64 + lane];
        sa2 += __int_as_float(p0.y);
        r0 += __uint_as_float(q0 << 16);
        r1 += __uint_as_float(q0 & 0xffff0000u);
    }

    float c0 = 0.f, c1 = 0.f;
    j = cs;
    for (; j + 8 <= ce; j += 8) {
        int ei[8];
#pragma unroll
        for (int k = 0; k < 8; ++k) ei[k] = col_edges[j + k];
        unsigned int q[8];
#pragma unroll
        for (int k = 0; k < 8; ++k) q[k] = eb[(size_t)ei[k] * 64 + lane];
#pragma unroll
        for (int k = 0; k < 8; ++k) {
            c0 += __uint_as_float(q[k] << 16);
            c1 += __uint_as_float(q[k] & 0xffff0000u);
        }
    }
    for (; j < ce; ++j) {
        int e0 = col_edges[j];
        unsigned int q0 = eb[(size_t)e0 * 64 + lane];
        c0 += __uint_as_float(q0 << 16);
        c1 += __uint_as_float(q0 & 0xffff0000u);
    }

    float2 w3 = *(const float2*)(attw + 256 + 2 * lane);
    float d3 = wsum(r0 * w3.x + r1 * w3.y);

    float degr = (float)(re - rs), degc = (float)(ce - cs);
    float satt = degr * (a1[node] + attb[0]) + sa2 + d3;
    float mr = 1.f / fmaxf(degr, 1.f);
    float mc = 1.f / fmaxf(degc, 1.f);

    float2 xv = *(const float2*)(xt + (size_t)node * D + 2 * lane);
    float s0 = fmaf(xv.x, satt, xv.x) + r0 * mr + c0 * mc;
    float s1 = fmaf(xv.y, satt, xv.y) + r1 * mr + c1 * mc;

    float n1 = fmaxf(sqrtf(wsum(s0 * s0 + s1 * s1)), 1e-15f);
    float th1 = tanhf(n1);
    float nrm1 = fminf(th1, 0.996f);
    float sc1 = nrm1 / n1;
    float lam = atanhf(fminf(nrm1, 1.f - 1e-7f)) / nrm1 * sc1;
    float t0 = fmaxf(lam * s0, 0.f);
    float t1 = fmaxf(lam * s1, 0.f);
    float n2 = fmaxf(sqrtf(wsum(t0 * t0 + t1 * t1)), 1e-15f);
    float th2 = tanhf(n2);
    float sc2 = fminf(th2, 0.996f) / n2;

    float2 o; o.x = sc2 * t0; o.y = sc2 * t1;
    *(float2*)(out + (size_t)node * D + 2 * lane) = o;
}

// ----------------------------------------------------------------
extern "C" void kernel_launch(void* const* d_in, const int* in_sizes, int n_in,
                              void* d_out, int out_size, void* d_ws, size_t ws_size,
                              hipStream_t stream) {
    const float* x    = (const float*)d_in[0];
    const int*   adj  = (const int*)d_in[1];
    const float* ea   = (const float*)d_in[2];
    const float* W    = (const float*)d_in[3];
    const float* bias = (const float*)d_in[4];
    const float* attw = (const float*)d_in[5];
    const float* attb = (const float*)d_in[6];
    float* out = (float*)d_out;

    const int N = in_sizes[0] / D;   // 50000
    const int E = in_sizes[2] / D;   // 800000

    float* ws = (float*)d_ws;
    float* xt   = ws;  ws += (size_t)N * D;
    float* a1   = ws;  ws += N;
    float* a2   = ws;  ws += N;
    float* hb   = ws;  ws += D;
    float* hbsc = ws;  ws += 4;
    float* Wt   = ws;  ws += D * D;
    unsigned int* eb = (unsigned int*)ws;  ws += (size_t)E * (D / 2);   // bf16x2, edge order
    int2* row_pairs  = (int2*)ws;          ws += (size_t)E * 2;          // (edge, a2bits)
    int* iws = (int*)ws;
    int* col_edges = iws; iws += E;
    int* flag    = iws;  iws += 4;
    int* cnt_r   = iws;  iws += N;   // cnt_r|cnt_c contiguous
    int* cnt_c   = iws;  iws += N;
    int* cur_r   = iws;  iws += N;
    int* cur_c   = iws;  iws += N;
    int* start_r = iws;  iws += N + 1;
    int* start_c = iws;  iws += N + 1;

    const int ZB = (2 * N + 255) / 256;
    initk<<<ZB + 6, 256, 0, stream>>>(adj, bias, attw, W, cnt_r, flag, hb, hbsc, Wt, 2 * N, ZB);

    // fusedA2: phase1 (3/8) | count (1/8) | convert-half1 (4/8)
    const int P1B = (N + 31) / 32;          // 1563
    const int NG_A = 544;                   // 8*544 = 4352 blocks; phase1 = 1632 >= P1B
    fusedA2<<<8 * NG_A, 256, 0, stream>>>(x, Wt, attw, hb, hbsc, adj, ea, flag,
                                          xt, a1, a2, cnt_r, cnt_c, eb, N, E, NG_A, P1B);

    scank<<<2, 1024, 0, stream>>>(cnt_r, cnt_c, start_r, start_c, cur_r, cur_c, N);

    // fusedD: fill (2/4) | convert-half2 (2/4)
    const int NG_D = 1024;                  // 4096 blocks
    fusedD<<<4 * NG_D, 256, 0, stream>>>(adj, a2, ea, cur_r, cur_c, row_pairs, col_edges,
                                         eb, flag, E, NG_D);

    gatherk<<<(N * 64 + 255) / 256, 256, 0, stream>>>(eb, attw, attb, xt, a1,
                                                      start_r, start_c, row_pairs, col_edges,
                                                      out, N);
}